// Round 1
// baseline (115.709 us; speedup 1.0000x reference)
//
#include <hip/hip_runtime.h>

// ---------------------------------------------------------------------------
// LocalityAwareCrossAttention  B=2, N=3136 (56x56), C=256, H=8, hd=32, R=3
// mask admits only 29 neighbors (dy^2+dx^2 <= 9) -> sparse local attention.
// Pipeline: convert->bf16 | fused QKV MFMA GEMM | local attn (wave/query) |
//           proj GEMM + bias.
// ---------------------------------------------------------------------------

typedef float  f32x4  __attribute__((ext_vector_type(4)));
typedef __bf16 bf16x8 __attribute__((ext_vector_type(8)));
typedef unsigned short u16x4 __attribute__((ext_vector_type(4)));
typedef unsigned short u16x8 __attribute__((ext_vector_type(8)));

#define Bb    2
#define Nn    3136
#define Cc    256
#define Mrows (Bb * Nn)          // 6272
#define BNC   (Bb * Nn * Cc)     // 1605632
#define CC    (Cc * Cc)          // 65536
#define GRID56 56

__device__ __forceinline__ unsigned short f2bf(float f) {
    unsigned u = __builtin_bit_cast(unsigned, f);
    u += 0x7fffu + ((u >> 16) & 1u);   // RNE
    return (unsigned short)(u >> 16);
}

// ---------------------------------------------------------------------------
// Kernel 0: fp32 -> bf16 conversion of x, x_kv, Wq, Wk, Wv, Wp (vector x4)
// units: x:401408, x_kv:401408, weights:4*16384  => 868352 total
// ---------------------------------------------------------------------------
__global__ __launch_bounds__(256) void convert_all(
    const float* __restrict__ x,  const float* __restrict__ xkv,
    const float* __restrict__ wq, const float* __restrict__ wk,
    const float* __restrict__ wv, const float* __restrict__ wp,
    unsigned short* __restrict__ xb,  unsigned short* __restrict__ xkvb,
    unsigned short* __restrict__ wqb, unsigned short* __restrict__ wkb,
    unsigned short* __restrict__ wvb, unsigned short* __restrict__ wpb)
{
    const int NX = BNC / 4;   // 401408
    const int NW = CC / 4;    // 16384
    int i = blockIdx.x * blockDim.x + threadIdx.x;
    const float* src; unsigned short* dst; int off;
    if (i < NX)            { src = x;   dst = xb;   off = i; }
    else if (i < 2 * NX)   { src = xkv; dst = xkvb; off = i - NX; }
    else {
        int j = i - 2 * NX;
        int wsel = j / NW; off = j - wsel * NW;
        src = (wsel == 0) ? wq : (wsel == 1) ? wk : (wsel == 2) ? wv : wp;
        dst = (wsel == 0) ? wqb : (wsel == 1) ? wkb : (wsel == 2) ? wvb : wpb;
    }
    f32x4 v = *reinterpret_cast<const f32x4*>(src + (size_t)off * 4);
    u16x4 o;
    o[0] = f2bf(v[0]); o[1] = f2bf(v[1]); o[2] = f2bf(v[2]); o[3] = f2bf(v[3]);
    *reinterpret_cast<u16x4*>(dst + (size_t)off * 4) = o;
}

// ---------------------------------------------------------------------------
// bf16 MFMA GEMM: Y[M,256] = A[M,256] @ W[256,256]^T (+bias)
// 64x64 tile, 4 waves, BK=32, LDS rows padded to 40 elems (2-way = free).
// ---------------------------------------------------------------------------
template<bool BIAS>
__device__ __forceinline__ void gemm_body(
    const unsigned short* __restrict__ A,
    const unsigned short* __restrict__ W,
    const float* __restrict__ bias,
    float* __restrict__ Y,
    int m0, int n0)
{
    constexpr int K = 256;
    constexpr int LDSW = 40;
    __shared__ unsigned short lA[64 * LDSW];
    __shared__ unsigned short lB[64 * LDSW];

    const int t    = threadIdx.x;
    const int lane = t & 63;
    const int wave = t >> 6;
    const int wm   = wave >> 1;      // 0..1  (32-row band)
    const int wn   = wave & 1;       // 0..1  (32-col band)
    const int srow = t >> 2;         // 0..63 staging row
    const int sseg = t & 3;          // 16B segment within row
    const int fr   = lane & 15;      // fragment row/col
    const int fk   = (lane >> 4) * 8;

    f32x4 acc[2][2] = {};

    for (int k0 = 0; k0 < K; k0 += 32) {
        u16x8 av = *reinterpret_cast<const u16x8*>(A + (size_t)(m0 + srow) * K + k0 + sseg * 8);
        u16x8 bv = *reinterpret_cast<const u16x8*>(W + (size_t)(n0 + srow) * K + k0 + sseg * 8);
        __syncthreads();
        *reinterpret_cast<u16x8*>(&lA[srow * LDSW + sseg * 8]) = av;
        *reinterpret_cast<u16x8*>(&lB[srow * LDSW + sseg * 8]) = bv;
        __syncthreads();

        bf16x8 af[2], bfr[2];
#pragma unroll
        for (int i = 0; i < 2; ++i) {
            af[i]  = *reinterpret_cast<const bf16x8*>(&lA[(wm * 32 + i * 16 + fr) * LDSW + fk]);
            bfr[i] = *reinterpret_cast<const bf16x8*>(&lB[(wn * 32 + i * 16 + fr) * LDSW + fk]);
        }
#pragma unroll
        for (int i = 0; i < 2; ++i)
#pragma unroll
            for (int j = 0; j < 2; ++j)
                acc[i][j] = __builtin_amdgcn_mfma_f32_16x16x32_bf16(af[i], bfr[j], acc[i][j], 0, 0, 0);
    }

#pragma unroll
    for (int i = 0; i < 2; ++i)
#pragma unroll
        for (int j = 0; j < 2; ++j) {
            int rbase = m0 + wm * 32 + i * 16 + (lane >> 4) * 4;
            int c     = n0 + wn * 32 + j * 16 + (lane & 15);
            float badd = BIAS ? bias[c] : 0.0f;
#pragma unroll
            for (int e = 0; e < 4; ++e)
                Y[(size_t)(rbase + e) * 256 + c] = acc[i][j][e] + badd;
        }
}

__global__ __launch_bounds__(256) void gemm_qkv_kernel(
    const unsigned short* __restrict__ xb, const unsigned short* __restrict__ xkvb,
    const unsigned short* __restrict__ wqb, const unsigned short* __restrict__ wkb,
    const unsigned short* __restrict__ wvb,
    float* __restrict__ Q, float* __restrict__ Kf, float* __restrict__ Vf)
{
    int z = blockIdx.z;
    const unsigned short* A = (z == 0) ? xb : xkvb;
    const unsigned short* W = (z == 0) ? wqb : (z == 1 ? wkb : wvb);
    float* Y = (z == 0) ? Q : (z == 1 ? Kf : Vf);
    gemm_body<false>(A, W, nullptr, Y, blockIdx.x * 64, blockIdx.y * 64);
}

__global__ __launch_bounds__(256) void gemm_proj_kernel(
    const unsigned short* __restrict__ Ab, const unsigned short* __restrict__ wpb,
    const float* __restrict__ bias, float* __restrict__ Y)
{
    gemm_body<true>(Ab, wpb, bias, Y, blockIdx.x * 64, blockIdx.y * 64);
}

// ---------------------------------------------------------------------------
// Local attention: one wave per query. lane l owns channels 4l..4l+3
// (head h = l/8; 8 lanes per head). Online softmax over <=29 neighbors.
// Output written as bf16 (input to proj GEMM).
// ---------------------------------------------------------------------------
__global__ __launch_bounds__(256) void attn_local(
    const float* __restrict__ Q, const float* __restrict__ K,
    const float* __restrict__ V, unsigned short* __restrict__ outb)
{
    const int wave = threadIdx.x >> 6;
    const int lane = threadIdx.x & 63;
    const int q = blockIdx.x * 4 + wave;          // 0..6271
    const int b = q / Nn;
    const int n = q - b * Nn;
    const int y = n / GRID56;
    const int x = n - y * GRID56;
    const float scale = 0.17677669529663687f;     // 1/sqrt(32)

    f32x4 qv = *reinterpret_cast<const f32x4*>(Q + (size_t)q * Cc + lane * 4);

    float m_run = -INFINITY, l_run = 0.0f;
    f32x4 acc = {0.0f, 0.0f, 0.0f, 0.0f};

#pragma unroll
    for (int dy = -3; dy <= 3; ++dy) {
        int yy = y + dy;
        if ((unsigned)yy >= (unsigned)GRID56) continue;
        int R = (dy == 0) ? 3 : ((dy == 3 || dy == -3) ? 0 : 2);
#pragma unroll
        for (int dx = -3; dx <= 3; ++dx) {
            if (dx < -R || dx > R) continue;
            int xx = x + dx;
            if ((unsigned)xx >= (unsigned)GRID56) continue;
            int m = b * Nn + yy * GRID56 + xx;
            f32x4 kv = *reinterpret_cast<const f32x4*>(K + (size_t)m * Cc + lane * 4);
            float p = qv[0] * kv[0] + qv[1] * kv[1] + qv[2] * kv[2] + qv[3] * kv[3];
            p += __shfl_xor(p, 1);
            p += __shfl_xor(p, 2);
            p += __shfl_xor(p, 4);               // per-head score now in all 8 lanes
            float s = p * scale;
            float m_new = fmaxf(m_run, s);
            float corr = __expf(m_run - m_new);  // exp(-inf)=0 on first hit
            float pe   = __expf(s - m_new);
            l_run = l_run * corr + pe;
            f32x4 vv = *reinterpret_cast<const f32x4*>(V + (size_t)m * Cc + lane * 4);
            acc[0] = acc[0] * corr + pe * vv[0];
            acc[1] = acc[1] * corr + pe * vv[1];
            acc[2] = acc[2] * corr + pe * vv[2];
            acc[3] = acc[3] * corr + pe * vv[3];
            m_run = m_new;
        }
    }
    float inv = 1.0f / l_run;
    u16x4 o;
    o[0] = f2bf(acc[0] * inv); o[1] = f2bf(acc[1] * inv);
    o[2] = f2bf(acc[2] * inv); o[3] = f2bf(acc[3] * inv);
    *reinterpret_cast<u16x4*>(outb + (size_t)q * Cc + lane * 4) = o;
}

// ---------------------------------------------------------------------------
extern "C" void kernel_launch(void* const* d_in, const int* in_sizes, int n_in,
                              void* d_out, int out_size, void* d_ws, size_t ws_size,
                              hipStream_t stream)
{
    const float* x   = (const float*)d_in[0];
    const float* xkv = (const float*)d_in[1];
    const float* Wq  = (const float*)d_in[2];
    const float* Wk  = (const float*)d_in[3];
    const float* Wv  = (const float*)d_in[4];
    const float* Wp  = (const float*)d_in[5];
    const float* bp  = (const float*)d_in[6];
    float* out = (float*)d_out;

    // workspace layout (~28.1 MB total)
    char* ws = (char*)d_ws;
    unsigned short* xb   = (unsigned short*)ws; ws += (size_t)BNC * 2;
    unsigned short* xkvb = (unsigned short*)ws; ws += (size_t)BNC * 2;
    unsigned short* wqb  = (unsigned short*)ws; ws += (size_t)CC * 2;
    unsigned short* wkb  = (unsigned short*)ws; ws += (size_t)CC * 2;
    unsigned short* wvb  = (unsigned short*)ws; ws += (size_t)CC * 2;
    unsigned short* wpb  = (unsigned short*)ws; ws += (size_t)CC * 2;
    float* Qf = (float*)ws; ws += (size_t)BNC * 4;
    float* Kf = (float*)ws; ws += (size_t)BNC * 4;
    float* Vf = (float*)ws; ws += (size_t)BNC * 4;
    unsigned short* attb = (unsigned short*)ws; ws += (size_t)BNC * 2;

    // 1) convert to bf16
    convert_all<<<3392, 256, 0, stream>>>(x, xkv, Wq, Wk, Wv, Wp,
                                          xb, xkvb, wqb, wkb, wvb, wpb);
    // 2) fused QKV projections
    dim3 gqkv(Mrows / 64, Cc / 64, 3);
    gemm_qkv_kernel<<<gqkv, 256, 0, stream>>>(xb, xkvb, wqb, wkb, wvb, Qf, Kf, Vf);
    // 3) local attention
    attn_local<<<Mrows / 4, 256, 0, stream>>>(Qf, Kf, Vf, attb);
    // 4) output projection + bias
    dim3 gproj(Mrows / 64, Cc / 64, 1);
    gemm_proj_kernel<<<gproj, 256, 0, stream>>>(attb, wpb, bp, out);
}

// Round 2
// 115.627 us; speedup vs baseline: 1.0007x; 1.0007x over previous
//
#include <hip/hip_runtime.h>

// ---------------------------------------------------------------------------
// LocalityAwareCrossAttention  B=2, N=3136 (56x56), C=256, H=8, hd=32, R=3
// Round 1: convert fused into GEMM staging; bf16 Q/K/V/att intermediates;
// BK=64. 3 kernels: fused-QKV GEMM | local attn | proj GEMM.
// ---------------------------------------------------------------------------

typedef float  f32x4  __attribute__((ext_vector_type(4)));
typedef __bf16 bf16x8 __attribute__((ext_vector_type(8)));
typedef unsigned short u16x4 __attribute__((ext_vector_type(4)));
typedef unsigned short u16x8 __attribute__((ext_vector_type(8)));

#define Nn    3136
#define Cc    256
#define Mrows 6272               // B*N
#define BNC   1605632            // B*N*C
#define GRID56 56

__device__ __forceinline__ unsigned short f2bf(float f) {
    unsigned u = __builtin_bit_cast(unsigned, f);
    u += 0x7fffu + ((u >> 16) & 1u);   // RNE
    return (unsigned short)(u >> 16);
}
__device__ __forceinline__ float bf2f(unsigned short h) {
    unsigned u = (unsigned)h << 16;
    return __builtin_bit_cast(float, u);
}

// ---------------------------------------------------------------------------
// MFMA GEMM: Y[M,256] = A[M,256] @ W[256,256]^T (+bias)
// 64x64 tile, 4 waves (2x2 of 32x32), BK=64, LDS rows padded to 72 elems.
// A is fp32 or bf16 (template); W always fp32, converted in staging.
// Output bf16 or fp32+bias (template).
// ---------------------------------------------------------------------------
template<bool A_BF16, bool OUT_BF16>
__device__ __forceinline__ void gemm_body(
    const void* __restrict__ Ap, const float* __restrict__ W,
    const float* __restrict__ bias, void* __restrict__ Yv,
    int m0, int n0)
{
    constexpr int LDSW = 72;                 // 64 + 8 pad (144 B rows, 16B-aligned)
    __shared__ unsigned short lA[64 * LDSW];
    __shared__ unsigned short lB[64 * LDSW];

    const int t    = threadIdx.x;
    const int lane = t & 63;
    const int wave = t >> 6;
    const int wm   = wave >> 1;              // 32-row band
    const int wn   = wave & 1;               // 32-col band
    const int srow = t >> 2;                 // staging row 0..63
    const int scol = (t & 3) * 16;           // staging col segment (16 elems)
    const int fr   = lane & 15;
    const int fk   = (lane >> 4) * 8;

    f32x4 acc[2][2] = {};

    for (int k0 = 0; k0 < 256; k0 += 64) {
        // ---- global loads (+ convert) into registers ----
        u16x8 astage[2], bstage[2];
        if constexpr (A_BF16) {
            const unsigned short* A = (const unsigned short*)Ap;
            astage[0] = *reinterpret_cast<const u16x8*>(A + (size_t)(m0 + srow) * 256 + k0 + scol);
            astage[1] = *reinterpret_cast<const u16x8*>(A + (size_t)(m0 + srow) * 256 + k0 + scol + 8);
        } else {
            const float* A = (const float*)Ap;
            f32x4 a4[4];
#pragma unroll
            for (int j = 0; j < 4; ++j)
                a4[j] = *reinterpret_cast<const f32x4*>(A + (size_t)(m0 + srow) * 256 + k0 + scol + j * 4);
#pragma unroll
            for (int j = 0; j < 4; ++j)
#pragma unroll
                for (int e = 0; e < 4; ++e)
                    astage[j >> 1][(j & 1) * 4 + e] = f2bf(a4[j][e]);
        }
        {
            f32x4 b4[4];
#pragma unroll
            for (int j = 0; j < 4; ++j)
                b4[j] = *reinterpret_cast<const f32x4*>(W + (size_t)(n0 + srow) * 256 + k0 + scol + j * 4);
#pragma unroll
            for (int j = 0; j < 4; ++j)
#pragma unroll
                for (int e = 0; e < 4; ++e)
                    bstage[j >> 1][(j & 1) * 4 + e] = f2bf(b4[j][e]);
        }

        __syncthreads();   // prior iter's LDS reads complete
        *reinterpret_cast<u16x8*>(&lA[srow * LDSW + scol])     = astage[0];
        *reinterpret_cast<u16x8*>(&lA[srow * LDSW + scol + 8]) = astage[1];
        *reinterpret_cast<u16x8*>(&lB[srow * LDSW + scol])     = bstage[0];
        *reinterpret_cast<u16x8*>(&lB[srow * LDSW + scol + 8]) = bstage[1];
        __syncthreads();

        // ---- fragments + MFMA (two K=32 halves) ----
        bf16x8 af[2][2], bfr[2][2];
#pragma unroll
        for (int i = 0; i < 2; ++i)
#pragma unroll
            for (int h = 0; h < 2; ++h) {
                af[i][h]  = *reinterpret_cast<const bf16x8*>(&lA[(wm * 32 + i * 16 + fr) * LDSW + h * 32 + fk]);
                bfr[i][h] = *reinterpret_cast<const bf16x8*>(&lB[(wn * 32 + i * 16 + fr) * LDSW + h * 32 + fk]);
            }
#pragma unroll
        for (int h = 0; h < 2; ++h)
#pragma unroll
            for (int i = 0; i < 2; ++i)
#pragma unroll
                for (int j = 0; j < 2; ++j)
                    acc[i][j] = __builtin_amdgcn_mfma_f32_16x16x32_bf16(af[i][h], bfr[j][h], acc[i][j], 0, 0, 0);
    }

    // ---- epilogue: C/D layout col=lane&15, row=(lane>>4)*4+e ----
#pragma unroll
    for (int i = 0; i < 2; ++i)
#pragma unroll
        for (int j = 0; j < 2; ++j) {
            int rbase = m0 + wm * 32 + i * 16 + (lane >> 4) * 4;
            int c     = n0 + wn * 32 + j * 16 + fr;
            if constexpr (OUT_BF16) {
                unsigned short* Y = (unsigned short*)Yv;
#pragma unroll
                for (int e = 0; e < 4; ++e)
                    Y[(size_t)(rbase + e) * 256 + c] = f2bf(acc[i][j][e]);
            } else {
                float* Y = (float*)Yv;
                float badd = bias[c];
#pragma unroll
                for (int e = 0; e < 4; ++e)
                    Y[(size_t)(rbase + e) * 256 + c] = acc[i][j][e] + badd;
            }
        }
}

__global__ __launch_bounds__(256) void gemm_qkv_kernel(
    const float* __restrict__ x, const float* __restrict__ xkv,
    const float* __restrict__ Wq, const float* __restrict__ Wk,
    const float* __restrict__ Wv,
    unsigned short* __restrict__ Qb, unsigned short* __restrict__ Kb,
    unsigned short* __restrict__ Vb)
{
    int z = blockIdx.z;
    const float* A = (z == 0) ? x : xkv;
    const float* W = (z == 0) ? Wq : (z == 1 ? Wk : Wv);
    unsigned short* Y = (z == 0) ? Qb : (z == 1 ? Kb : Vb);
    gemm_body<false, true>(A, W, nullptr, Y, blockIdx.x * 64, blockIdx.y * 64);
}

__global__ __launch_bounds__(256) void gemm_proj_kernel(
    const unsigned short* __restrict__ attb, const float* __restrict__ Wp,
    const float* __restrict__ bias, float* __restrict__ Y)
{
    gemm_body<true, false>(attb, Wp, bias, Y, blockIdx.x * 64, blockIdx.y * 64);
}

// ---------------------------------------------------------------------------
// Local attention: one wave per query; lane l owns channels 4l..4l+3
// (8 lanes per head). Online softmax over <=29 neighbors. bf16 in/out.
// ---------------------------------------------------------------------------
__global__ __launch_bounds__(256) void attn_local(
    const unsigned short* __restrict__ Q, const unsigned short* __restrict__ K,
    const unsigned short* __restrict__ V, unsigned short* __restrict__ outb)
{
    const int wave = threadIdx.x >> 6;
    const int lane = threadIdx.x & 63;
    const int q = blockIdx.x * 4 + wave;          // 0..6271
    const int b = q / Nn;
    const int n = q - b * Nn;
    const int y = n / GRID56;
    const int x = n - y * GRID56;
    const float scale = 0.17677669529663687f;     // 1/sqrt(32)

    u16x4 qr = *reinterpret_cast<const u16x4*>(Q + (size_t)q * Cc + lane * 4);
    float q0 = bf2f(qr[0]), q1 = bf2f(qr[1]), q2 = bf2f(qr[2]), q3 = bf2f(qr[3]);

    float m_run = -INFINITY, l_run = 0.0f;
    f32x4 acc = {0.0f, 0.0f, 0.0f, 0.0f};

#pragma unroll
    for (int dy = -3; dy <= 3; ++dy) {
        int yy = y + dy;
        if ((unsigned)yy >= (unsigned)GRID56) continue;
        int R = (dy == 0) ? 3 : ((dy == 3 || dy == -3) ? 0 : 2);
#pragma unroll
        for (int dx = -3; dx <= 3; ++dx) {
            if (dx < -R || dx > R) continue;
            int xx = x + dx;
            if ((unsigned)xx >= (unsigned)GRID56) continue;
            int m = b * Nn + yy * GRID56 + xx;
            u16x4 kr = *reinterpret_cast<const u16x4*>(K + (size_t)m * Cc + lane * 4);
            u16x4 vr = *reinterpret_cast<const u16x4*>(V + (size_t)m * Cc + lane * 4);
            float p = q0 * bf2f(kr[0]) + q1 * bf2f(kr[1]) + q2 * bf2f(kr[2]) + q3 * bf2f(kr[3]);
            p += __shfl_xor(p, 1);
            p += __shfl_xor(p, 2);
            p += __shfl_xor(p, 4);               // per-head score in all 8 lanes
            float s = p * scale;
            float m_new = fmaxf(m_run, s);
            float corr = __expf(m_run - m_new);  // exp(-inf)=0 on first hit
            float pe   = __expf(s - m_new);
            l_run = l_run * corr + pe;
            acc[0] = acc[0] * corr + pe * bf2f(vr[0]);
            acc[1] = acc[1] * corr + pe * bf2f(vr[1]);
            acc[2] = acc[2] * corr + pe * bf2f(vr[2]);
            acc[3] = acc[3] * corr + pe * bf2f(vr[3]);
            m_run = m_new;
        }
    }
    float inv = 1.0f / l_run;
    u16x4 o;
    o[0] = f2bf(acc[0] * inv); o[1] = f2bf(acc[1] * inv);
    o[2] = f2bf(acc[2] * inv); o[3] = f2bf(acc[3] * inv);
    *reinterpret_cast<u16x4*>(outb + (size_t)q * Cc + lane * 4) = o;
}

// ---------------------------------------------------------------------------
extern "C" void kernel_launch(void* const* d_in, const int* in_sizes, int n_in,
                              void* d_out, int out_size, void* d_ws, size_t ws_size,
                              hipStream_t stream)
{
    const float* x   = (const float*)d_in[0];
    const float* xkv = (const float*)d_in[1];
    const float* Wq  = (const float*)d_in[2];
    const float* Wk  = (const float*)d_in[3];
    const float* Wv  = (const float*)d_in[4];
    const float* Wp  = (const float*)d_in[5];
    const float* bp  = (const float*)d_in[6];
    float* out = (float*)d_out;

    // workspace: Qb,Kb,Vb,attb bf16 (4 x 3.2 MB)
    char* ws = (char*)d_ws;
    unsigned short* Qb   = (unsigned short*)ws; ws += (size_t)BNC * 2;
    unsigned short* Kb   = (unsigned short*)ws; ws += (size_t)BNC * 2;
    unsigned short* Vb   = (unsigned short*)ws; ws += (size_t)BNC * 2;
    unsigned short* attb = (unsigned short*)ws; ws += (size_t)BNC * 2;

    // 1) fused QKV projections (fp32 in, bf16 out, convert in staging)
    dim3 gqkv(Mrows / 64, Cc / 64, 3);
    gemm_qkv_kernel<<<gqkv, 256, 0, stream>>>(x, xkv, Wq, Wk, Wv, Qb, Kb, Vb);
    // 2) local attention (bf16 in/out)
    attn_local<<<Mrows / 4, 256, 0, stream>>>(Qb, Kb, Vb, attb);
    // 3) output projection + bias (bf16 A, fp32 out)
    dim3 gproj(Mrows / 64, Cc / 64, 1);
    gemm_proj_kernel<<<gproj, 256, 0, stream>>>(attb, Wp, bp, out);
}